// Round 5
// baseline (241.451 us; speedup 1.0000x reference)
//
#include <hip/hip_runtime.h>
#include <hip/hip_bf16.h>
#include <math.h>

#define BB   4
#define LQ   2048
#define LK   2048
#define HD   8
#define VD   64
#define HV   512
#define OUTD 512
#define SP   72          // padded LDS row stride in bf16 elems (144 B, 16B-aligned)
#define NT   16          // tiles of 64 k per k-half (1024/64)

typedef __attribute__((ext_vector_type(8))) short  bf16x8;
typedef __attribute__((ext_vector_type(4))) float  f32x4;
typedef __attribute__((ext_vector_type(4))) unsigned int u32x4;

static_assert(sizeof(__hip_bfloat162) == 4, "bf162 must be 4 bytes");

static __device__ __forceinline__ unsigned short f2bf(float f) {
    unsigned u = __builtin_bit_cast(unsigned, f);
    unsigned r = (u + 0x7fffu + ((u >> 16) & 1u)) >> 16;
    return (unsigned short)r;
}

static __device__ __forceinline__ unsigned pk2bf(float lo, float hi) {
    __hip_bfloat162 h = __float22bfloat162_rn(make_float2(lo, hi));
    unsigned r;
    __builtin_memcpy(&r, &h, 4);   // not bit_cast: bf162 isn't trivially copyable
    return r;
}

// ---------------- values fp32 [b][k][h][v] -> bf16 [b][h][v][k] ----------------
__global__ __launch_bounds__(256) void cvt_vals(
    const float* __restrict__ vals, unsigned short* __restrict__ vals_t)
{
    __shared__ unsigned short st[64 * SP];   // [v][k] tile
    const int tid = threadIdx.x;
    const int kt = blockIdx.x, h = blockIdx.y, b = blockIdx.z;

    const int k  = tid >> 2;
    const int vb = (tid & 3) * 16;
    const float* src = vals + (((size_t)(b * LK + kt * 64 + k) * HD + h)) * VD + vb;
    float4 f0 = *(const float4*)(src);
    float4 f1 = *(const float4*)(src + 4);
    float4 f2 = *(const float4*)(src + 8);
    float4 f3 = *(const float4*)(src + 12);
    const float fv[16] = {f0.x,f0.y,f0.z,f0.w, f1.x,f1.y,f1.z,f1.w,
                          f2.x,f2.y,f2.z,f2.w, f3.x,f3.y,f3.z,f3.w};
#pragma unroll
    for (int j = 0; j < 16; ++j) st[(vb + j) * SP + k] = f2bf(fv[j]);
    __syncthreads();

    const int v  = tid >> 2;
    const int kb = (tid & 3) * 16;
    uint4 o0 = *(const uint4*)&st[v * SP + kb];
    uint4 o1 = *(const uint4*)&st[v * SP + kb + 8];
    unsigned short* dst = vals_t + ((size_t)((b * HD + h) * VD + v)) * LK + kt * 64 + kb;
    *(uint4*)dst       = o0;
    *(uint4*)(dst + 8) = o1;
}

// ---------------- fused gaussian-score attention, head-merged + k-split, no-spill ----
// grid (LQ/16, BB) = 512 blocks, 512 threads = 8 waves.
// wave = (head-pair hp, k-half kh): 16 q-rows x 2 heads x 1024 k.
// Register budget (the round-4 lesson): cap = 128 (launch_bounds 512,4).
//   acc 32 + V-halfset 32 + a-frags 16 + score temps ~30 + misc ~15 = ~125. No dbuf.
__global__ __launch_bounds__(512, 4) void attend5(
    const float* __restrict__ qpos,
    const float* __restrict__ kpos,
    const unsigned short* __restrict__ vals_t,
    const int*   __restrict__ kmask,
    const float* __restrict__ ls,
    unsigned short* __restrict__ attended)
{
    __shared__ __align__(16) float s_kx[LK];
    __shared__ __align__(16) float s_ky[LK];
    __shared__ __align__(16) float s_kz[LK];
    __shared__ __align__(16) float s_mrg[4][34 * 64];   // [hp][j*64+lane]

    const int tid = threadIdx.x;
    const int qt = blockIdx.x, b = blockIdx.y;
    const int q0 = qt * 16;

    // stage all k-positions for this batch once; fold mask into kx
    for (int i = tid; i < LK; i += 512) {
        const float* kp = kpos + (size_t)(b * LK + i) * 3;
        float kx = kp[0];
        if (kmask[b * LK + i]) kx = 3.0e37f;   // d2 -> inf -> score exactly 0
        s_kx[i] = kx; s_ky[i] = kp[1]; s_kz[i] = kp[2];
    }
    __syncthreads();

    const int wave = tid >> 6;
    const int lane = tid & 63;
    const int ln   = lane & 15;
    const int kq   = lane >> 4;
    const int hp   = wave >> 1;
    const int h0   = hp * 2;
    const int kh   = wave & 1;
    const int kb0  = kh * (LK / 2);

    const float* qp = qpos + (size_t)(b * LQ + q0 + ln) * 3;
    const float qx = qp[0], qy = qp[1], qz = qp[2];

    const float ls0 = ls[h0], ls1 = ls[h0 + 1];
    const float negc0 = -1.0f / (ls0 * ls0);
    const float negc1 = -1.0f / (ls1 * ls1);

    const unsigned short* vt0 = vals_t + ((size_t)((b * HD + h0)     * VD) + ln) * LK + kq * 8;
    const unsigned short* vt1 = vals_t + ((size_t)((b * HD + h0 + 1) * VD) + ln) * LK + kq * 8;

    f32x4 acc0[4], acc1[4];
#pragma unroll
    for (int n = 0; n < 4; ++n) {
        acc0[n] = (f32x4){0.f, 0.f, 0.f, 0.f};
        acc1[n] = (f32x4){0.f, 0.f, 0.f, 0.f};
    }
    float pden0 = 0.f, pden1 = 0.f;

#pragma unroll 1
    for (int t = 0; t < NT; ++t) {
        const int kt = kb0 + t * 64;

        // ---- V half-set 1 (n = 0,1): issue early, consumed after score phase ----
        bf16x8 vA_h0_n0_s0 = *(const bf16x8*)(vt0 + (size_t)0 * 16 * LK + kt);
        bf16x8 vA_h0_n0_s1 = *(const bf16x8*)(vt0 + (size_t)0 * 16 * LK + kt + 32);
        bf16x8 vA_h0_n1_s0 = *(const bf16x8*)(vt0 + (size_t)1 * 16 * LK + kt);
        bf16x8 vA_h0_n1_s1 = *(const bf16x8*)(vt0 + (size_t)1 * 16 * LK + kt + 32);
        bf16x8 vA_h1_n0_s0 = *(const bf16x8*)(vt1 + (size_t)0 * 16 * LK + kt);
        bf16x8 vA_h1_n0_s1 = *(const bf16x8*)(vt1 + (size_t)0 * 16 * LK + kt + 32);
        bf16x8 vA_h1_n1_s0 = *(const bf16x8*)(vt1 + (size_t)1 * 16 * LK + kt);
        bf16x8 vA_h1_n1_s1 = *(const bf16x8*)(vt1 + (size_t)1 * 16 * LK + kt + 32);

        // ---- score phase: j-pair at a time, minimal transient registers ----
        bf16x8 a0[2], a1[2];
#pragma unroll
        for (int s = 0; s < 2; ++s) {
            const int kb = kt + s * 32 + kq * 8;
            float kxa[8], kya[8], kza[8];
            *(float4*)&kxa[0] = *(const float4*)&s_kx[kb];
            *(float4*)&kxa[4] = *(const float4*)&s_kx[kb + 4];
            *(float4*)&kya[0] = *(const float4*)&s_ky[kb];
            *(float4*)&kya[4] = *(const float4*)&s_ky[kb + 4];
            *(float4*)&kza[0] = *(const float4*)&s_kz[kb];
            *(float4*)&kza[4] = *(const float4*)&s_kz[kb + 4];
            u32x4 p0, p1;
#pragma unroll
            for (int jj = 0; jj < 4; ++jj) {
                const int j0 = 2 * jj, j1 = 2 * jj + 1;
                const float dx0 = qx - kxa[j0], dy0 = qy - kya[j0], dz0 = qz - kza[j0];
                const float dx1 = qx - kxa[j1], dy1 = qy - kya[j1], dz1 = qz - kza[j1];
                const float d2a = fmaf(dx0, dx0, fmaf(dy0, dy0, dz0 * dz0));
                const float d2b = fmaf(dx1, dx1, fmaf(dy1, dy1, dz1 * dz1));
                const float e00 = __expf(d2a * negc0);
                const float e01 = __expf(d2b * negc0);
                const float e10 = __expf(d2a * negc1);
                const float e11 = __expf(d2b * negc1);
                pden0 += e00; pden0 += e01;
                pden1 += e10; pden1 += e11;
                p0[jj] = pk2bf(e00, e01);
                p1[jj] = pk2bf(e10, e11);
            }
            a0[s] = __builtin_bit_cast(bf16x8, p0);
            a1[s] = __builtin_bit_cast(bf16x8, p1);
        }

        // ---- MFMA n=0,1 (half-set 1) ----
        acc0[0] = __builtin_amdgcn_mfma_f32_16x16x32_bf16(a0[0], vA_h0_n0_s0, acc0[0], 0, 0, 0);
        acc0[0] = __builtin_amdgcn_mfma_f32_16x16x32_bf16(a0[1], vA_h0_n0_s1, acc0[0], 0, 0, 0);
        acc0[1] = __builtin_amdgcn_mfma_f32_16x16x32_bf16(a0[0], vA_h0_n1_s0, acc0[1], 0, 0, 0);
        acc0[1] = __builtin_amdgcn_mfma_f32_16x16x32_bf16(a0[1], vA_h0_n1_s1, acc0[1], 0, 0, 0);
        acc1[0] = __builtin_amdgcn_mfma_f32_16x16x32_bf16(a1[0], vA_h1_n0_s0, acc1[0], 0, 0, 0);
        acc1[0] = __builtin_amdgcn_mfma_f32_16x16x32_bf16(a1[1], vA_h1_n0_s1, acc1[0], 0, 0, 0);
        acc1[1] = __builtin_amdgcn_mfma_f32_16x16x32_bf16(a1[0], vA_h1_n1_s0, acc1[1], 0, 0, 0);
        acc1[1] = __builtin_amdgcn_mfma_f32_16x16x32_bf16(a1[1], vA_h1_n1_s1, acc1[1], 0, 0, 0);

        // ---- V half-set 2 (n = 2,3); scheduler hoists into the MFMAs above as regs allow ----
        bf16x8 vB_h0_n2_s0 = *(const bf16x8*)(vt0 + (size_t)2 * 16 * LK + kt);
        bf16x8 vB_h0_n2_s1 = *(const bf16x8*)(vt0 + (size_t)2 * 16 * LK + kt + 32);
        bf16x8 vB_h0_n3_s0 = *(const bf16x8*)(vt0 + (size_t)3 * 16 * LK + kt);
        bf16x8 vB_h0_n3_s1 = *(const bf16x8*)(vt0 + (size_t)3 * 16 * LK + kt + 32);
        bf16x8 vB_h1_n2_s0 = *(const bf16x8*)(vt1 + (size_t)2 * 16 * LK + kt);
        bf16x8 vB_h1_n2_s1 = *(const bf16x8*)(vt1 + (size_t)2 * 16 * LK + kt + 32);
        bf16x8 vB_h1_n3_s0 = *(const bf16x8*)(vt1 + (size_t)3 * 16 * LK + kt);
        bf16x8 vB_h1_n3_s1 = *(const bf16x8*)(vt1 + (size_t)3 * 16 * LK + kt + 32);

        acc0[2] = __builtin_amdgcn_mfma_f32_16x16x32_bf16(a0[0], vB_h0_n2_s0, acc0[2], 0, 0, 0);
        acc0[2] = __builtin_amdgcn_mfma_f32_16x16x32_bf16(a0[1], vB_h0_n2_s1, acc0[2], 0, 0, 0);
        acc0[3] = __builtin_amdgcn_mfma_f32_16x16x32_bf16(a0[0], vB_h0_n3_s0, acc0[3], 0, 0, 0);
        acc0[3] = __builtin_amdgcn_mfma_f32_16x16x32_bf16(a0[1], vB_h0_n3_s1, acc0[3], 0, 0, 0);
        acc1[2] = __builtin_amdgcn_mfma_f32_16x16x32_bf16(a1[0], vB_h1_n2_s0, acc1[2], 0, 0, 0);
        acc1[2] = __builtin_amdgcn_mfma_f32_16x16x32_bf16(a1[1], vB_h1_n2_s1, acc1[2], 0, 0, 0);
        acc1[3] = __builtin_amdgcn_mfma_f32_16x16x32_bf16(a1[0], vB_h1_n3_s0, acc1[3], 0, 0, 0);
        acc1[3] = __builtin_amdgcn_mfma_f32_16x16x32_bf16(a1[1], vB_h1_n3_s1, acc1[3], 0, 0, 0);
    }

    // merge k-half partials: kh=1 writes, kh=0 adds
    if (kh == 1) {
#pragma unroll
        for (int n = 0; n < 4; ++n)
#pragma unroll
            for (int r = 0; r < 4; ++r) {
                s_mrg[hp][(n * 4 + r) * 64 + lane]      = acc0[n][r];
                s_mrg[hp][(16 + n * 4 + r) * 64 + lane] = acc1[n][r];
            }
        s_mrg[hp][32 * 64 + lane] = pden0;
        s_mrg[hp][33 * 64 + lane] = pden1;
    }
    __syncthreads();
    if (kh == 0) {
#pragma unroll
        for (int n = 0; n < 4; ++n)
#pragma unroll
            for (int r = 0; r < 4; ++r) {
                acc0[n][r] += s_mrg[hp][(n * 4 + r) * 64 + lane];
                acc1[n][r] += s_mrg[hp][(16 + n * 4 + r) * 64 + lane];
            }
        pden0 += s_mrg[hp][32 * 64 + lane];
        pden1 += s_mrg[hp][33 * 64 + lane];

        // reduce across kq groups (lanes ln, ln+16, ln+32, ln+48)
        pden0 += __shfl_xor(pden0, 16);
        pden0 += __shfl_xor(pden0, 32);
        pden1 += __shfl_xor(pden1, 16);
        pden1 += __shfl_xor(pden1, 32);

        // epilogue rows are kq*4+r; fetch that row's denominator
        f32x4 inv0, inv1;
#pragma unroll
        for (int r = 0; r < 4; ++r) {
            inv0[r] = 1.0f / (__shfl(pden0, kq * 4 + r) + 1e-5f);
            inv1[r] = 1.0f / (__shfl(pden1, kq * 4 + r) + 1e-5f);
        }

        unsigned short* op = attended
            + (size_t)(b * LQ + q0 + kq * 4) * HV + h0 * VD + ln;
#pragma unroll
        for (int n = 0; n < 4; ++n) {
#pragma unroll
            for (int r = 0; r < 4; ++r) {
                op[(size_t)r * HV + n * 16]      = f2bf(acc0[n][r] * inv0[r]);
                op[(size_t)r * HV + VD + n * 16] = f2bf(acc1[n][r] * inv1[r]);
            }
        }
    }
}

// ---------------- projection: C[8192][512] = A_bf16[8192][512] @ W[512][512]^T ----------------
__global__ __launch_bounds__(256) void proj2(
    const unsigned short* __restrict__ A,
    const float* __restrict__ W,
    float* __restrict__ C)
{
    __shared__ unsigned short sA[64 * SP];
    __shared__ unsigned short sW[64 * SP];

    const int tid = threadIdx.x;
    const int n0 = blockIdx.x * 64, m0 = blockIdx.y * 64;
    const int wave = tid >> 6, lane = tid & 63;
    const int ln = lane & 15, kq = lane >> 4;

    const int am = tid >> 3, ac = tid & 7;          // A staging
    const int wn = tid >> 2, wk = (tid & 3) * 16;   // W staging

    f32x4 acc[4];
#pragma unroll
    for (int n = 0; n < 4; ++n) acc[n] = (f32x4){0.f, 0.f, 0.f, 0.f};

    for (int k0 = 0; k0 < 512; k0 += 64) {
        __syncthreads();
        {
            const unsigned short* asrc = A + (size_t)(m0 + am) * 512 + k0 + ac * 8;
            uint4 a0 = *(const uint4*)asrc;
            uint4 a1 = *(const uint4*)(asrc + (size_t)32 * 512);
            *(uint4*)&sA[am * SP + ac * 8]        = a0;
            *(uint4*)&sA[(am + 32) * SP + ac * 8] = a1;
        }
        {
            const float* wsrc = W + (size_t)(n0 + wn) * 512 + k0 + wk;
            float4 w0 = *(const float4*)(wsrc);
            float4 w1 = *(const float4*)(wsrc + 4);
            float4 w2 = *(const float4*)(wsrc + 8);
            float4 w3 = *(const float4*)(wsrc + 12);
            const float wf[16] = {w0.x,w0.y,w0.z,w0.w, w1.x,w1.y,w1.z,w1.w,
                                  w2.x,w2.y,w2.z,w2.w, w3.x,w3.y,w3.z,w3.w};
            unsigned pk[8];
#pragma unroll
            for (int j = 0; j < 8; ++j)
                pk[j] = (unsigned)f2bf(wf[2 * j]) | ((unsigned)f2bf(wf[2 * j + 1]) << 16);
            *(uint4*)&sW[wn * SP + wk]     = make_uint4(pk[0], pk[1], pk[2], pk[3]);
            *(uint4*)&sW[wn * SP + wk + 8] = make_uint4(pk[4], pk[5], pk[6], pk[7]);
        }
        __syncthreads();

        const unsigned short* ap = &sA[(wave * 16 + ln) * SP + kq * 8];
        const bf16x8 a0 = *(const bf16x8*)(ap);
        const bf16x8 a1 = *(const bf16x8*)(ap + 32);
#pragma unroll
        for (int n = 0; n < 4; ++n) {
            const unsigned short* bp = &sW[(n * 16 + ln) * SP + kq * 8];
            const bf16x8 b0 = *(const bf16x8*)(bp);
            const bf16x8 b1 = *(const bf16x8*)(bp + 32);
            acc[n] = __builtin_amdgcn_mfma_f32_16x16x32_bf16(a0, b0, acc[n], 0, 0, 0);
            acc[n] = __builtin_amdgcn_mfma_f32_16x16x32_bf16(a1, b1, acc[n], 0, 0, 0);
        }
    }

#pragma unroll
    for (int n = 0; n < 4; ++n) {
#pragma unroll
        for (int r = 0; r < 4; ++r) {
            C[(size_t)(m0 + wave * 16 + kq * 4 + r) * 512 + n0 + n * 16 + ln] = acc[n][r];
        }
    }
}

extern "C" void kernel_launch(void* const* d_in, const int* in_sizes, int n_in,
                              void* d_out, int out_size, void* d_ws, size_t ws_size,
                              hipStream_t stream) {
    const float* qpos  = (const float*)d_in[0];
    const float* kpos  = (const float*)d_in[1];
    const float* vals  = (const float*)d_in[2];
    const int*   kmask = (const int*)  d_in[3];
    const float* ls    = (const float*)d_in[4];
    const float* wout  = (const float*)d_in[5];
    float* out = (float*)d_out;

    unsigned short* vals_t   = (unsigned short*)d_ws;            // 8 MiB
    unsigned short* attended = vals_t + (size_t)4 * 1024 * 1024; // 8 MiB

    cvt_vals<<<dim3(32, HD, BB), 256, 0, stream>>>(vals, vals_t);
    attend5 <<<dim3(LQ / 16, BB), 512, 0, stream>>>(qpos, kpos, vals_t, kmask, ls, attended);
    proj2   <<<dim3(OUTD / 64, (BB * LQ) / 64), 256, 0, stream>>>(attended, wout, out);
}

// Round 6
// 215.319 us; speedup vs baseline: 1.1214x; 1.1214x over previous
//
#include <hip/hip_runtime.h>
#include <hip/hip_bf16.h>
#include <math.h>

#define BB   4
#define LQ   2048
#define LK   2048
#define HD   8
#define VD   64
#define HV   512
#define OUTD 512
#define SP   72          // padded LDS row stride in bf16 elems (144 B, 16B-aligned)
#define NT   16          // tiles of 64 k per k-half (1024/64)

typedef __attribute__((ext_vector_type(8))) short  bf16x8;
typedef __attribute__((ext_vector_type(4))) float  f32x4;
typedef __attribute__((ext_vector_type(4))) unsigned int u32x4;

static_assert(sizeof(__hip_bfloat162) == 4, "bf162 must be 4 bytes");

static __device__ __forceinline__ unsigned short f2bf(float f) {
    unsigned u = __builtin_bit_cast(unsigned, f);
    unsigned r = (u + 0x7fffu + ((u >> 16) & 1u)) >> 16;
    return (unsigned short)r;
}

static __device__ __forceinline__ unsigned pk2bf(float lo, float hi) {
    __hip_bfloat162 h = __float22bfloat162_rn(make_float2(lo, hi));
    unsigned r;
    __builtin_memcpy(&r, &h, 4);   // not bit_cast: bf162 isn't trivially copyable
    return r;
}

// ---------------- values fp32 [b][k][h][v] -> bf16 [b][h][v][k] ----------------
__global__ __launch_bounds__(256) void cvt_vals(
    const float* __restrict__ vals, unsigned short* __restrict__ vals_t)
{
    __shared__ unsigned short st[64 * SP];   // [v][k] tile
    const int tid = threadIdx.x;
    const int kt = blockIdx.x, h = blockIdx.y, b = blockIdx.z;

    const int k  = tid >> 2;
    const int vb = (tid & 3) * 16;
    const float* src = vals + (((size_t)(b * LK + kt * 64 + k) * HD + h)) * VD + vb;
    float4 f0 = *(const float4*)(src);
    float4 f1 = *(const float4*)(src + 4);
    float4 f2 = *(const float4*)(src + 8);
    float4 f3 = *(const float4*)(src + 12);
    const float fv[16] = {f0.x,f0.y,f0.z,f0.w, f1.x,f1.y,f1.z,f1.w,
                          f2.x,f2.y,f2.z,f2.w, f3.x,f3.y,f3.z,f3.w};
#pragma unroll
    for (int j = 0; j < 16; ++j) st[(vb + j) * SP + k] = f2bf(fv[j]);
    __syncthreads();

    const int v  = tid >> 2;
    const int kb = (tid & 3) * 16;
    uint4 o0 = *(const uint4*)&st[v * SP + kb];
    uint4 o1 = *(const uint4*)&st[v * SP + kb + 8];
    unsigned short* dst = vals_t + ((size_t)((b * HD + h) * VD + v)) * LK + kt * 64 + kb;
    *(uint4*)dst       = o0;
    *(uint4*)(dst + 8) = o1;
}

// ---------------- fused gaussian-score attention, head-merged + k-split ----------------
// grid flat 512 blocks, 512 threads = 8 waves. wave = (head-pair hp, k-half kh).
// Round-6 spill fix: amdgpu_waves_per_eu(4,4) pins the register budget at 128
// (r4/r5 allocator targeted 8 waves/EU -> 64 VGPRs -> ~55 MB scratch traffic),
// and live V fragments cut to cur(8)+prefetch(8) with 8 precomputed base pointers.
// XCD swizzle: b = bid&3 so each XCD (bid%8 round-robin) streams ONE 2 MB V slab (L2-fits).
__attribute__((amdgpu_waves_per_eu(4, 4)))
__global__ void __launch_bounds__(512) attend6(
    const float* __restrict__ qpos,
    const float* __restrict__ kpos,
    const unsigned short* __restrict__ vals_t,
    const int*   __restrict__ kmask,
    const float* __restrict__ ls,
    unsigned short* __restrict__ attended)
{
    __shared__ __align__(16) float s_kx[LK];
    __shared__ __align__(16) float s_ky[LK];
    __shared__ __align__(16) float s_kz[LK];
    __shared__ __align__(16) float s_mrg[4][34 * 64];   // [hp][j*64+lane]

    const int tid = threadIdx.x;
    const int bid = blockIdx.x;
    const int b  = bid & 3;
    const int qt = (bid >> 3) + ((bid >> 2) & 1) * 64;   // bijective over 0..127
    const int q0 = qt * 16;

    // stage all k-positions for this batch once; fold mask into kx
    for (int i = tid; i < LK; i += 512) {
        const float* kp = kpos + (size_t)(b * LK + i) * 3;
        float kx = kp[0];
        if (kmask[b * LK + i]) kx = 3.0e37f;   // d2 -> inf -> score exactly 0
        s_kx[i] = kx; s_ky[i] = kp[1]; s_kz[i] = kp[2];
    }
    __syncthreads();

    const int wave = tid >> 6;
    const int lane = tid & 63;
    const int ln   = lane & 15;
    const int kq   = lane >> 4;
    const int hp   = wave >> 1;
    const int h0   = hp * 2;
    const int kh   = wave & 1;
    const int kb0  = kh * (LK / 2);

    const float* qp = qpos + (size_t)(b * LQ + q0 + ln) * 3;
    const float qx = qp[0], qy = qp[1], qz = qp[2];

    const float ls0 = ls[h0], ls1 = ls[h0 + 1];
    const float negc0 = -1.0f / (ls0 * ls0);
    const float negc1 = -1.0f / (ls1 * ls1);

    // 8 base pointers (n-block x head), kb0/kq/ln folded in: per-tile offset = t*64 (+32)
    const unsigned short* const vb0 = vals_t + ((size_t)((b * HD + h0)     * VD) + ln) * LK + kb0 + kq * 8;
    const unsigned short* const vb1 = vals_t + ((size_t)((b * HD + h0 + 1) * VD) + ln) * LK + kb0 + kq * 8;
    const unsigned short* const pa0 = vb0;
    const unsigned short* const pa1 = vb0 + (size_t)16 * LK;
    const unsigned short* const pa2 = vb0 + (size_t)32 * LK;
    const unsigned short* const pa3 = vb0 + (size_t)48 * LK;
    const unsigned short* const pb0 = vb1;
    const unsigned short* const pb1 = vb1 + (size_t)16 * LK;
    const unsigned short* const pb2 = vb1 + (size_t)32 * LK;
    const unsigned short* const pb3 = vb1 + (size_t)48 * LK;

    f32x4 acc0[4], acc1[4];
#pragma unroll
    for (int n = 0; n < 4; ++n) {
        acc0[n] = (f32x4){0.f, 0.f, 0.f, 0.f};
        acc1[n] = (f32x4){0.f, 0.f, 0.f, 0.f};
    }
    float pden0 = 0.f, pden1 = 0.f;

#pragma unroll 1
    for (int t = 0; t < NT; ++t) {
        const int to = t * 64;

        // ---- n=0 V loads issued before score phase (score math covers latency) ----
        bf16x8 x0 = *(const bf16x8*)(pa0 + to);
        bf16x8 x1 = *(const bf16x8*)(pa0 + to + 32);
        bf16x8 x2 = *(const bf16x8*)(pb0 + to);
        bf16x8 x3 = *(const bf16x8*)(pb0 + to + 32);

        // ---- score phase: j-pair streaming, minimal transients ----
        bf16x8 a0[2], a1[2];
#pragma unroll
        for (int s = 0; s < 2; ++s) {
            const int kb = kb0 + to + s * 32 + kq * 8;
            float kxa[8], kya[8], kza[8];
            *(float4*)&kxa[0] = *(const float4*)&s_kx[kb];
            *(float4*)&kxa[4] = *(const float4*)&s_kx[kb + 4];
            *(float4*)&kya[0] = *(const float4*)&s_ky[kb];
            *(float4*)&kya[4] = *(const float4*)&s_ky[kb + 4];
            *(float4*)&kza[0] = *(const float4*)&s_kz[kb];
            *(float4*)&kza[4] = *(const float4*)&s_kz[kb + 4];
            u32x4 p0, p1;
#pragma unroll
            for (int jj = 0; jj < 4; ++jj) {
                const int j0 = 2 * jj, j1 = 2 * jj + 1;
                const float dx0 = qx - kxa[j0], dy0 = qy - kya[j0], dz0 = qz - kza[j0];
                const float dx1 = qx - kxa[j1], dy1 = qy - kya[j1], dz1 = qz - kza[j1];
                const float d2a = fmaf(dx0, dx0, fmaf(dy0, dy0, dz0 * dz0));
                const float d2b = fmaf(dx1, dx1, fmaf(dy1, dy1, dz1 * dz1));
                const float e00 = __expf(d2a * negc0);
                const float e01 = __expf(d2b * negc0);
                const float e10 = __expf(d2a * negc1);
                const float e11 = __expf(d2b * negc1);
                pden0 += e00; pden0 += e01;
                pden1 += e10; pden1 += e11;
                p0[jj] = pk2bf(e00, e01);
                p1[jj] = pk2bf(e10, e11);
            }
            a0[s] = __builtin_bit_cast(bf16x8, p0);
            a1[s] = __builtin_bit_cast(bf16x8, p1);
        }

        // ---- n-pipelined MFMA: cur(x) / prefetch(y), 16 live V regs max ----
        bf16x8 y0 = *(const bf16x8*)(pa1 + to);
        bf16x8 y1 = *(const bf16x8*)(pa1 + to + 32);
        bf16x8 y2 = *(const bf16x8*)(pb1 + to);
        bf16x8 y3 = *(const bf16x8*)(pb1 + to + 32);

        acc0[0] = __builtin_amdgcn_mfma_f32_16x16x32_bf16(a0[0], x0, acc0[0], 0, 0, 0);
        acc0[0] = __builtin_amdgcn_mfma_f32_16x16x32_bf16(a0[1], x1, acc0[0], 0, 0, 0);
        acc1[0] = __builtin_amdgcn_mfma_f32_16x16x32_bf16(a1[0], x2, acc1[0], 0, 0, 0);
        acc1[0] = __builtin_amdgcn_mfma_f32_16x16x32_bf16(a1[1], x3, acc1[0], 0, 0, 0);

        x0 = *(const bf16x8*)(pa2 + to);
        x1 = *(const bf16x8*)(pa2 + to + 32);
        x2 = *(const bf16x8*)(pb2 + to);
        x3 = *(const bf16x8*)(pb2 + to + 32);

        acc0[1] = __builtin_amdgcn_mfma_f32_16x16x32_bf16(a0[0], y0, acc0[1], 0, 0, 0);
        acc0[1] = __builtin_amdgcn_mfma_f32_16x16x32_bf16(a0[1], y1, acc0[1], 0, 0, 0);
        acc1[1] = __builtin_amdgcn_mfma_f32_16x16x32_bf16(a1[0], y2, acc1[1], 0, 0, 0);
        acc1[1] = __builtin_amdgcn_mfma_f32_16x16x32_bf16(a1[1], y3, acc1[1], 0, 0, 0);

        y0 = *(const bf16x8*)(pa3 + to);
        y1 = *(const bf16x8*)(pa3 + to + 32);
        y2 = *(const bf16x8*)(pb3 + to);
        y3 = *(const bf16x8*)(pb3 + to + 32);

        acc0[2] = __builtin_amdgcn_mfma_f32_16x16x32_bf16(a0[0], x0, acc0[2], 0, 0, 0);
        acc0[2] = __builtin_amdgcn_mfma_f32_16x16x32_bf16(a0[1], x1, acc0[2], 0, 0, 0);
        acc1[2] = __builtin_amdgcn_mfma_f32_16x16x32_bf16(a1[0], x2, acc1[2], 0, 0, 0);
        acc1[2] = __builtin_amdgcn_mfma_f32_16x16x32_bf16(a1[1], x3, acc1[2], 0, 0, 0);

        acc0[3] = __builtin_amdgcn_mfma_f32_16x16x32_bf16(a0[0], y0, acc0[3], 0, 0, 0);
        acc0[3] = __builtin_amdgcn_mfma_f32_16x16x32_bf16(a0[1], y1, acc0[3], 0, 0, 0);
        acc1[3] = __builtin_amdgcn_mfma_f32_16x16x32_bf16(a1[0], y2, acc1[3], 0, 0, 0);
        acc1[3] = __builtin_amdgcn_mfma_f32_16x16x32_bf16(a1[1], y3, acc1[3], 0, 0, 0);
    }

    // merge k-half partials: kh=1 writes, kh=0 adds
    if (kh == 1) {
#pragma unroll
        for (int n = 0; n < 4; ++n)
#pragma unroll
            for (int r = 0; r < 4; ++r) {
                s_mrg[hp][(n * 4 + r) * 64 + lane]      = acc0[n][r];
                s_mrg[hp][(16 + n * 4 + r) * 64 + lane] = acc1[n][r];
            }
        s_mrg[hp][32 * 64 + lane] = pden0;
        s_mrg[hp][33 * 64 + lane] = pden1;
    }
    __syncthreads();
    if (kh == 0) {
#pragma unroll
        for (int n = 0; n < 4; ++n)
#pragma unroll
            for (int r = 0; r < 4; ++r) {
                acc0[n][r] += s_mrg[hp][(n * 4 + r) * 64 + lane];
                acc1[n][r] += s_mrg[hp][(16 + n * 4 + r) * 64 + lane];
            }
        pden0 += s_mrg[hp][32 * 64 + lane];
        pden1 += s_mrg[hp][33 * 64 + lane];

        // reduce across kq groups (lanes ln, ln+16, ln+32, ln+48)
        pden0 += __shfl_xor(pden0, 16);
        pden0 += __shfl_xor(pden0, 32);
        pden1 += __shfl_xor(pden1, 16);
        pden1 += __shfl_xor(pden1, 32);

        // epilogue rows are kq*4+r; fetch that row's denominator
        f32x4 inv0, inv1;
#pragma unroll
        for (int r = 0; r < 4; ++r) {
            inv0[r] = 1.0f / (__shfl(pden0, kq * 4 + r) + 1e-5f);
            inv1[r] = 1.0f / (__shfl(pden1, kq * 4 + r) + 1e-5f);
        }

        unsigned short* op = attended
            + (size_t)(b * LQ + q0 + kq * 4) * HV + h0 * VD + ln;
#pragma unroll
        for (int n = 0; n < 4; ++n) {
#pragma unroll
            for (int r = 0; r < 4; ++r) {
                op[(size_t)r * HV + n * 16]      = f2bf(acc0[n][r] * inv0[r]);
                op[(size_t)r * HV + VD + n * 16] = f2bf(acc1[n][r] * inv1[r]);
            }
        }
    }
}

// ---------------- projection: C[8192][512] = A_bf16[8192][512] @ W[512][512]^T ----------------
__global__ __launch_bounds__(256) void proj2(
    const unsigned short* __restrict__ A,
    const float* __restrict__ W,
    float* __restrict__ C)
{
    __shared__ unsigned short sA[64 * SP];
    __shared__ unsigned short sW[64 * SP];

    const int tid = threadIdx.x;
    const int n0 = blockIdx.x * 64, m0 = blockIdx.y * 64;
    const int wave = tid >> 6, lane = tid & 63;
    const int ln = lane & 15, kq = lane >> 4;

    const int am = tid >> 3, ac = tid & 7;          // A staging
    const int wn = tid >> 2, wk = (tid & 3) * 16;   // W staging

    f32x4 acc[4];
#pragma unroll
    for (int n = 0; n < 4; ++n) acc[n] = (f32x4){0.f, 0.f, 0.f, 0.f};

    for (int k0 = 0; k0 < 512; k0 += 64) {
        __syncthreads();
        {
            const unsigned short* asrc = A + (size_t)(m0 + am) * 512 + k0 + ac * 8;
            uint4 a0 = *(const uint4*)asrc;
            uint4 a1 = *(const uint4*)(asrc + (size_t)32 * 512);
            *(uint4*)&sA[am * SP + ac * 8]        = a0;
            *(uint4*)&sA[(am + 32) * SP + ac * 8] = a1;
        }
        {
            const float* wsrc = W + (size_t)(n0 + wn) * 512 + k0 + wk;
            float4 w0 = *(const float4*)(wsrc);
            float4 w1 = *(const float4*)(wsrc + 4);
            float4 w2 = *(const float4*)(wsrc + 8);
            float4 w3 = *(const float4*)(wsrc + 12);
            const float wf[16] = {w0.x,w0.y,w0.z,w0.w, w1.x,w1.y,w1.z,w1.w,
                                  w2.x,w2.y,w2.z,w2.w, w3.x,w3.y,w3.z,w3.w};
            unsigned pk[8];
#pragma unroll
            for (int j = 0; j < 8; ++j)
                pk[j] = (unsigned)f2bf(wf[2 * j]) | ((unsigned)f2bf(wf[2 * j + 1]) << 16);
            *(uint4*)&sW[wn * SP + wk]     = make_uint4(pk[0], pk[1], pk[2], pk[3]);
            *(uint4*)&sW[wn * SP + wk + 8] = make_uint4(pk[4], pk[5], pk[6], pk[7]);
        }
        __syncthreads();

        const unsigned short* ap = &sA[(wave * 16 + ln) * SP + kq * 8];
        const bf16x8 a0 = *(const bf16x8*)(ap);
        const bf16x8 a1 = *(const bf16x8*)(ap + 32);
#pragma unroll
        for (int n = 0; n < 4; ++n) {
            const unsigned short* bp = &sW[(n * 16 + ln) * SP + kq * 8];
            const bf16x8 b0 = *(const bf16x8*)(bp);
            const bf16x8 b1 = *(const bf16x8*)(bp + 32);
            acc[n] = __builtin_amdgcn_mfma_f32_16x16x32_bf16(a0, b0, acc[n], 0, 0, 0);
            acc[n] = __builtin_amdgcn_mfma_f32_16x16x32_bf16(a1, b1, acc[n], 0, 0, 0);
        }
    }

#pragma unroll
    for (int n = 0; n < 4; ++n) {
#pragma unroll
        for (int r = 0; r < 4; ++r) {
            C[(size_t)(m0 + wave * 16 + kq * 4 + r) * 512 + n0 + n * 16 + ln] = acc[n][r];
        }
    }
}

extern "C" void kernel_launch(void* const* d_in, const int* in_sizes, int n_in,
                              void* d_out, int out_size, void* d_ws, size_t ws_size,
                              hipStream_t stream) {
    const float* qpos  = (const float*)d_in[0];
    const float* kpos  = (const float*)d_in[1];
    const float* vals  = (const float*)d_in[2];
    const int*   kmask = (const int*)  d_in[3];
    const float* ls    = (const float*)d_in[4];
    const float* wout  = (const float*)d_in[5];
    float* out = (float*)d_out;

    unsigned short* vals_t   = (unsigned short*)d_ws;            // 8 MiB
    unsigned short* attended = vals_t + (size_t)4 * 1024 * 1024; // 8 MiB

    cvt_vals<<<dim3(32, HD, BB), 256, 0, stream>>>(vals, vals_t);
    attend6 <<<dim3(512), 512, 0, stream>>>(qpos, kpos, vals_t, kmask, ls, attended);
    proj2   <<<dim3(OUTD / 64, (BB * LQ) / 64), 256, 0, stream>>>(attended, wout, out);
}